// Round 1
// baseline (543.240 us; speedup 1.0000x reference)
//
#include <hip/hip_runtime.h>

// Problem constants (from reference):
//   obj   : [1, 2048, 2048] fp32      (in_sizes[0] = 4,194,304)
//   waves : [4, 1024, 128, 128] fp32  (in_sizes[1] = 67,108,864)
//   pos   : [1024, 2] int32           (in_sizes[2] = 2,048)
// Outputs (concatenated in d_out, fp32):
//   patches     : [1024, 1, 128, 128] = 16,777,216 elems
//   object_norm : [2048, 2048]        =  4,194,304 elems

#define NMODES 4
#define NB     1024
#define PH     128
#define PW     128
#define OH     2048
#define OW     2048

__global__ __launch_bounds__(256) void fused_crop_scatter(
    const float* __restrict__ obj,
    const float* __restrict__ waves,
    const int*   __restrict__ pos,
    float* __restrict__ patches,
    float* __restrict__ norm)
{
    // One thread per quad of 4 consecutive w elements.
    // Total quads = NB*PH*PW/4 = 4,194,304. Quads per batch = PH*PW/4 = 4096.
    const int q     = blockIdx.x * blockDim.x + threadIdx.x;
    const int b     = q >> 12;          // / 4096
    const int local = q & 4095;
    const int h     = local >> 5;       // 32 quads per row (PW/4)
    const int w     = (local & 31) << 2;

    const int r0 = pos[b * 2 + 0];
    const int c0 = pos[b * 2 + 1];

    const int HW   = PH * PW;           // 16384
    const int base = b * HW + h * PW + w;   // index into waves mode-0 / patches

    // patch_norm = sum over 4 modes of waves^2 (vectorized float4 loads,
    // 16B-aligned since w % 4 == 0)
    const float4 v0 = *reinterpret_cast<const float4*>(waves + base);
    const float4 v1 = *reinterpret_cast<const float4*>(waves + base + 1 * NB * HW);
    const float4 v2 = *reinterpret_cast<const float4*>(waves + base + 2 * NB * HW);
    const float4 v3 = *reinterpret_cast<const float4*>(waves + base + 3 * NB * HW);

    float4 acc;
    acc.x = v0.x * v0.x + v1.x * v1.x + v2.x * v2.x + v3.x * v3.x;
    acc.y = v0.y * v0.y + v1.y * v1.y + v2.y * v2.y + v3.y * v3.y;
    acc.z = v0.z * v0.z + v1.z * v1.z + v2.z * v2.z + v3.z * v3.z;
    acc.w = v0.w * v0.w + v1.w * v1.w + v2.w * v2.w + v3.w * v3.w;

    // Object index for this quad (c0 arbitrary -> scalar obj loads; obj is
    // 16 MiB and fully L2/L3 resident so these are cache hits).
    const int oidx = (r0 + h) * OW + (c0 + w);

    // batch_crop gather -> coalesced, aligned float4 store
    float4 p;
    p.x = obj[oidx + 0];
    p.y = obj[oidx + 1];
    p.z = obj[oidx + 2];
    p.w = obj[oidx + 3];
    *reinterpret_cast<float4*>(patches + base) = p;

    // overlap_intensity scatter-add (device-scope fp32 atomics)
    atomicAdd(&norm[oidx + 0], acc.x);
    atomicAdd(&norm[oidx + 1], acc.y);
    atomicAdd(&norm[oidx + 2], acc.z);
    atomicAdd(&norm[oidx + 3], acc.w);
}

extern "C" void kernel_launch(void* const* d_in, const int* in_sizes, int n_in,
                              void* d_out, int out_size, void* d_ws, size_t ws_size,
                              hipStream_t stream) {
    const float* obj   = (const float*)d_in[0];
    const float* waves = (const float*)d_in[1];
    const int*   pos   = (const int*)d_in[2];

    float* patches = (float*)d_out;                       // 16,777,216 elems
    float* norm    = (float*)d_out + (size_t)NB * PH * PW; // 4,194,304 elems

    // d_out is poisoned 0xAA before every timed launch: zero the scatter
    // destination (async on stream -> graph-capture safe).
    hipMemsetAsync(norm, 0, (size_t)OH * OW * sizeof(float), stream);

    const int quads  = NB * PH * PW / 4;  // 4,194,304
    const int block  = 256;
    const int grid   = quads / block;     // 16384
    fused_crop_scatter<<<grid, block, 0, stream>>>(obj, waves, pos, patches, norm);
}

// Round 2
// 512.166 us; speedup vs baseline: 1.0607x; 1.0607x over previous
//
#include <hip/hip_runtime.h>

// Problem constants (from reference):
//   obj   : [1, 2048, 2048] fp32      (in_sizes[0] = 4,194,304)
//   waves : [4, 1024, 128, 128] fp32  (in_sizes[1] = 67,108,864)
//   pos   : [1024, 2] int32           (in_sizes[2] = 2,048), values in [0,1920)
// Outputs (concatenated in d_out, fp32):
//   patches     : [1024, 1, 128, 128] = 16,777,216 elems
//   object_norm : [2048, 2048]        =  4,194,304 elems

#define NMODES 4
#define NB     1024
#define PH     128
#define PW     128
#define OH     2048
#define OW     2048

// Tiling for the scatter->gather inversion
#define TS       64              // object tile size (64x64)
#define NT_X     (OW / TS)       // 32
#define NT_Y     (OH / TS)       // 32
#define NT       (NT_X * NT_Y)   // 1024 tiles
#define CAP      128             // max batches listed per tile (avg ~10)

// ---------------------------------------------------------------------------
// Kernel A: patch crop (gather from obj) + batch->tile binning.
// One thread per quad of 4 consecutive w elements (aligned float4).
// Threads with global id < NB additionally bin their batch into tile lists.
// ---------------------------------------------------------------------------
__global__ __launch_bounds__(256) void crop_and_bin(
    const float* __restrict__ obj,
    const int*   __restrict__ pos,
    float* __restrict__ patches,
    int*   __restrict__ tile_cnt,
    int*   __restrict__ tile_list)
{
    const int q = blockIdx.x * blockDim.x + threadIdx.x;

    // --- binning (first NB threads only; ~9 tiny int atomics each) ---
    if (q < NB) {
        const int r0 = pos[2 * q];
        const int c0 = pos[2 * q + 1];
        const int ty0 = r0 >> 6, ty1 = (r0 + PH - 1) >> 6;
        const int tx0 = c0 >> 6, tx1 = (c0 + PW - 1) >> 6;
        for (int ty = ty0; ty <= ty1; ++ty)
            for (int tx = tx0; tx <= tx1; ++tx) {
                const int t = ty * NT_X + tx;
                const int idx = atomicAdd(&tile_cnt[t], 1);
                if (idx < CAP) tile_list[t * CAP + idx] = q;
            }
    }

    // --- crop: patches[b,h,w..w+3] = obj[r0+h, c0+w..w+3] ---
    const int b     = q >> 12;          // quads per batch = PH*PW/4 = 4096
    const int local = q & 4095;
    const int h     = local >> 5;       // 32 quads per row
    const int w     = (local & 31) << 2;

    const int r0 = pos[b * 2 + 0];
    const int c0 = pos[b * 2 + 1];

    const int oidx = (r0 + h) * OW + (c0 + w);
    float4 p;
    p.x = obj[oidx + 0];
    p.y = obj[oidx + 1];
    p.z = obj[oidx + 2];
    p.w = obj[oidx + 3];
    *reinterpret_cast<float4*>(patches + b * (PH * PW) + h * PW + w) = p;
}

// ---------------------------------------------------------------------------
// Kernel B: object_norm via gather. One block per 64x64 tile; stage the
// tile's batch list in LDS; each thread owns 16 pixels (64-wide rows ->
// coalesced waves reads & norm writes). Each waves element is read exactly
// once across the whole grid; each norm pixel written exactly once.
// ---------------------------------------------------------------------------
__global__ __launch_bounds__(256) void norm_gather(
    const float* __restrict__ waves,
    const int*   __restrict__ pos,
    const int*   __restrict__ tile_cnt,
    const int*   __restrict__ tile_list,
    float* __restrict__ norm)
{
    const int t  = blockIdx.x;
    const int Y0 = (t >> 5) * TS;       // tile row origin
    const int X0 = (t & 31) * TS;       // tile col origin

    __shared__ int s_base[CAP];         // b * PH*PW
    __shared__ int s_r[CAP];
    __shared__ int s_c[CAP];

    const int count = min(tile_cnt[t], CAP);
    for (int i = threadIdx.x; i < count; i += 256) {
        const int b = tile_list[t * CAP + i];
        s_base[i] = b * (PH * PW);
        s_r[i]    = pos[2 * b];
        s_c[i]    = pos[2 * b + 1];
    }
    __syncthreads();

    const int x  = threadIdx.x & 63;    // 64 lanes span one tile row
    const int y0 = threadIdx.x >> 6;    // 4 row-phases
    const int X  = X0 + x;

    const int MS = NB * PH * PW;        // mode stride in elements

    for (int yy = y0; yy < TS; yy += 4) {
        const int Y = Y0 + yy;
        float acc = 0.0f;
        for (int i = 0; i < count; ++i) {
            const int dr = Y - s_r[i];  // broadcast LDS reads (conflict-free)
            const int dc = X - s_c[i];
            if ((unsigned)dr < (unsigned)PH && (unsigned)dc < (unsigned)PW) {
                const float* wp = waves + s_base[i] + dr * PW + dc;
                const float a0 = wp[0];
                const float a1 = wp[MS];
                const float a2 = wp[2 * MS];
                const float a3 = wp[3 * MS];
                acc += a0 * a0 + a1 * a1 + a2 * a2 + a3 * a3;
            }
        }
        norm[Y * OW + X] = acc;         // every pixel written exactly once
    }
}

extern "C" void kernel_launch(void* const* d_in, const int* in_sizes, int n_in,
                              void* d_out, int out_size, void* d_ws, size_t ws_size,
                              hipStream_t stream) {
    const float* obj   = (const float*)d_in[0];
    const float* waves = (const float*)d_in[1];
    const int*   pos   = (const int*)d_in[2];

    float* patches = (float*)d_out;                        // 16,777,216 elems
    float* norm    = (float*)d_out + (size_t)NB * PH * PW; // 4,194,304 elems

    // Workspace layout: [tile_cnt: NT ints][tile_list: NT*CAP ints] = 516 KB
    int* tile_cnt  = (int*)d_ws;
    int* tile_list = tile_cnt + NT;

    // ws is poisoned 0xAA each call -> zero the counters (4 KB, async).
    hipMemsetAsync(tile_cnt, 0, NT * sizeof(int), stream);

    const int quads = NB * PH * PW / 4;  // 4,194,304
    crop_and_bin<<<quads / 256, 256, 0, stream>>>(obj, pos, patches,
                                                  tile_cnt, tile_list);
    // Stream order guarantees tile lists are complete & visible device-wide.
    norm_gather<<<NT, 256, 0, stream>>>(waves, pos, tile_cnt, tile_list, norm);
}

// Round 3
// 417.071 us; speedup vs baseline: 1.3025x; 1.2280x over previous
//
#include <hip/hip_runtime.h>

// Problem constants (from reference):
//   obj   : [1, 2048, 2048] fp32      (in_sizes[0] = 4,194,304)
//   waves : [4, 1024, 128, 128] fp32  (in_sizes[1] = 67,108,864)
//   pos   : [1024, 2] int32           (in_sizes[2] = 2,048), values in [0,1920)
// Outputs (concatenated in d_out, fp32):
//   patches     : [1024, 1, 128, 128] = 16,777,216 elems
//   object_norm : [2048, 2048]        =  4,194,304 elems

#define NMODES 4
#define NB     1024
#define PH     128
#define PW     128
#define OH     2048
#define OW     2048

// Tiling for the scatter->gather inversion
#define TS       64              // object tile size (64x64)
#define NT_X     (OW / TS)       // 32
#define NT_Y     (OH / TS)       // 32
#define NT       (NT_X * NT_Y)   // 1024 tiles
#define CAP      128             // max batches listed per tile (avg ~10)
#define SLICES   8               // row-slices per tile -> 8192 blocks

// ---------------------------------------------------------------------------
// Kernel A: patch crop (gather from obj) + batch->tile binning.
// One thread per quad of 4 consecutive w elements (aligned float4).
// Threads with global id < NB additionally bin their batch into tile lists.
// ---------------------------------------------------------------------------
__global__ __launch_bounds__(256) void crop_and_bin(
    const float* __restrict__ obj,
    const int*   __restrict__ pos,
    float* __restrict__ patches,
    int*   __restrict__ tile_cnt,
    int*   __restrict__ tile_list)
{
    const int q = blockIdx.x * blockDim.x + threadIdx.x;

    // --- binning (first NB threads only; ~9 tiny int atomics each) ---
    if (q < NB) {
        const int r0 = pos[2 * q];
        const int c0 = pos[2 * q + 1];
        const int ty0 = r0 >> 6, ty1 = (r0 + PH - 1) >> 6;
        const int tx0 = c0 >> 6, tx1 = (c0 + PW - 1) >> 6;
        for (int ty = ty0; ty <= ty1; ++ty)
            for (int tx = tx0; tx <= tx1; ++tx) {
                const int t = ty * NT_X + tx;
                const int idx = atomicAdd(&tile_cnt[t], 1);
                if (idx < CAP) tile_list[t * CAP + idx] = q;
            }
    }

    // --- crop: patches[b,h,w..w+3] = obj[r0+h, c0+w..w+3] ---
    const int b     = q >> 12;          // quads per batch = PH*PW/4 = 4096
    const int local = q & 4095;
    const int h     = local >> 5;       // 32 quads per row
    const int w     = (local & 31) << 2;

    const int r0 = pos[b * 2 + 0];
    const int c0 = pos[b * 2 + 1];

    const int oidx = (r0 + h) * OW + (c0 + w);
    float4 p;
    p.x = obj[oidx + 0];
    p.y = obj[oidx + 1];
    p.z = obj[oidx + 2];
    p.w = obj[oidx + 3];
    *reinterpret_cast<float4*>(patches + b * (PH * PW) + h * PW + w) = p;
}

// ---------------------------------------------------------------------------
// Kernel B: object_norm via gather. 8192 blocks = 1024 tiles x 8 row-slices
// (64 wide x 8 tall each). 256 threads/block; each thread owns 2 pixels
// (rows phase and phase+4 of the slice) -> 8 independent gather loads per
// covering batch (ILP), wave-uniform row test, at-most-one column split.
// Each waves element is read exactly once device-wide; each norm pixel
// written exactly once -> zero fp32 atomics.
// ---------------------------------------------------------------------------
__global__ __launch_bounds__(256) void norm_gather(
    const float* __restrict__ waves,
    const int*   __restrict__ pos,
    const int*   __restrict__ tile_cnt,
    const int*   __restrict__ tile_list,
    float* __restrict__ norm)
{
    const int blk = blockIdx.x;
    const int t   = blk >> 3;           // tile id
    const int s   = blk & 7;            // row-slice within tile
    const int Y0  = (t >> 5) * TS + s * (TS / SLICES);
    const int X0  = (t & 31) * TS;

    __shared__ int s_base[CAP];         // b * PH*PW
    __shared__ int s_r[CAP];
    __shared__ int s_c[CAP];

    const int count = min(tile_cnt[t], CAP);
    for (int i = threadIdx.x; i < count; i += 256) {
        const int b = tile_list[t * CAP + i];
        s_base[i] = b * (PH * PW);
        s_r[i]    = pos[2 * b];
        s_c[i]    = pos[2 * b + 1];
    }
    __syncthreads();

    const int x     = threadIdx.x & 63; // 64 lanes span one tile row
    const int phase = threadIdx.x >> 6; // 0..3
    const int X     = X0 + x;
    const int Ya    = Y0 + phase;       // first owned row
    const int Yb    = Ya + 4;           // second owned row

    const int MS = NB * PH * PW;        // mode stride in elements

    float acc_a = 0.0f;
    float acc_b = 0.0f;

    for (int i = 0; i < count; ++i) {
        const int dra = Ya - s_r[i];    // broadcast LDS reads (conflict-free)
        const int drb = Yb - s_r[i];
        const int dc  = X  - s_c[i];
        const bool cok = (unsigned)dc < (unsigned)PW;
        if (cok && (unsigned)dra < (unsigned)PH) {
            const float* wp = waves + s_base[i] + dra * PW + dc;
            const float a0 = wp[0];
            const float a1 = wp[MS];
            const float a2 = wp[2 * MS];
            const float a3 = wp[3 * MS];
            acc_a += a0 * a0 + a1 * a1 + a2 * a2 + a3 * a3;
        }
        if (cok && (unsigned)drb < (unsigned)PH) {
            const float* wp = waves + s_base[i] + drb * PW + dc;
            const float b0 = wp[0];
            const float b1 = wp[MS];
            const float b2 = wp[2 * MS];
            const float b3 = wp[3 * MS];
            acc_b += b0 * b0 + b1 * b1 + b2 * b2 + b3 * b3;
        }
    }

    norm[Ya * OW + X] = acc_a;          // every pixel written exactly once
    norm[Yb * OW + X] = acc_b;
}

extern "C" void kernel_launch(void* const* d_in, const int* in_sizes, int n_in,
                              void* d_out, int out_size, void* d_ws, size_t ws_size,
                              hipStream_t stream) {
    const float* obj   = (const float*)d_in[0];
    const float* waves = (const float*)d_in[1];
    const int*   pos   = (const int*)d_in[2];

    float* patches = (float*)d_out;                        // 16,777,216 elems
    float* norm    = (float*)d_out + (size_t)NB * PH * PW; // 4,194,304 elems

    // Workspace layout: [tile_cnt: NT ints][tile_list: NT*CAP ints] = 516 KB
    int* tile_cnt  = (int*)d_ws;
    int* tile_list = tile_cnt + NT;

    // ws is poisoned 0xAA each call -> zero the counters (4 KB, async).
    hipMemsetAsync(tile_cnt, 0, NT * sizeof(int), stream);

    const int quads = NB * PH * PW / 4;  // 4,194,304
    crop_and_bin<<<quads / 256, 256, 0, stream>>>(obj, pos, patches,
                                                  tile_cnt, tile_list);
    // Stream order guarantees tile lists are complete & visible device-wide.
    norm_gather<<<NT * SLICES, 256, 0, stream>>>(waves, pos, tile_cnt,
                                                 tile_list, norm);
}

// Round 4
// 414.291 us; speedup vs baseline: 1.3113x; 1.0067x over previous
//
#include <hip/hip_runtime.h>

// Problem constants (from reference):
//   obj   : [1, 2048, 2048] fp32      (in_sizes[0] = 4,194,304)
//   waves : [4, 1024, 128, 128] fp32  (in_sizes[1] = 67,108,864)
//   pos   : [1024, 2] int32           (in_sizes[2] = 2,048), values in [0,1920)
// Outputs (concatenated in d_out, fp32):
//   patches     : [1024, 1, 128, 128] = 16,777,216 elems
//   object_norm : [2048, 2048]        =  4,194,304 elems

#define NMODES 4
#define NB     1024
#define PH     128
#define PW     128
#define OH     2048
#define OW     2048

// Tiling for the scatter->gather inversion
#define TS       64              // object tile size (64x64)
#define NT_X     (OW / TS)       // 32
#define NT_Y     (OH / TS)       // 32
#define NT       (NT_X * NT_Y)   // 1024 tiles
#define CAP      128             // max batches listed per tile (avg ~10)
#define SLICES   8               // row-slices per tile -> 8192 blocks
#define UNROLL   4

// ---------------------------------------------------------------------------
// Kernel A: patch crop (gather from obj) + batch->tile binning.
// One thread per quad of 4 consecutive w elements (aligned float4).
// Threads with global id < NB additionally bin their batch into tile lists.
// ---------------------------------------------------------------------------
__global__ __launch_bounds__(256) void crop_and_bin(
    const float* __restrict__ obj,
    const int*   __restrict__ pos,
    float* __restrict__ patches,
    int*   __restrict__ tile_cnt,
    int*   __restrict__ tile_list)
{
    const int q = blockIdx.x * blockDim.x + threadIdx.x;

    // --- binning (first NB threads only; ~9 tiny int atomics each) ---
    if (q < NB) {
        const int r0 = pos[2 * q];
        const int c0 = pos[2 * q + 1];
        const int ty0 = r0 >> 6, ty1 = (r0 + PH - 1) >> 6;
        const int tx0 = c0 >> 6, tx1 = (c0 + PW - 1) >> 6;
        for (int ty = ty0; ty <= ty1; ++ty)
            for (int tx = tx0; tx <= tx1; ++tx) {
                const int t = ty * NT_X + tx;
                const int idx = atomicAdd(&tile_cnt[t], 1);
                if (idx < CAP) tile_list[t * CAP + idx] = q;
            }
    }

    // --- crop: patches[b,h,w..w+3] = obj[r0+h, c0+w..w+3] ---
    const int b     = q >> 12;          // quads per batch = PH*PW/4 = 4096
    const int local = q & 4095;
    const int h     = local >> 5;       // 32 quads per row
    const int w     = (local & 31) << 2;

    const int r0 = pos[b * 2 + 0];
    const int c0 = pos[b * 2 + 1];

    const int oidx = (r0 + h) * OW + (c0 + w);
    float4 p;
    p.x = obj[oidx + 0];
    p.y = obj[oidx + 1];
    p.z = obj[oidx + 2];
    p.w = obj[oidx + 3];
    *reinterpret_cast<float4*>(patches + b * (PH * PW) + h * PW + w) = p;
}

// ---------------------------------------------------------------------------
// Kernel B: object_norm via gather. 8192 blocks = 1024 tiles x 8 row-slices
// (64 wide x 8 tall each). 256 threads/block; each thread owns 2 pixels.
// BRANCHLESS inner loop: dr/dc are clamped into [0,PH)x[0,PW) so every load
// is in-bounds and issued unconditionally; the accumulate is masked. This
// lets the compiler pipeline loads across UNROLL=4 iterations (up to 32
// outstanding loads/wave) instead of one waitcnt-serialized latency per
// covering batch. Tile lists are padded to a multiple of UNROLL with
// far-away dummy positions (mask always 0, clamped loads hit waves[0..]).
// ---------------------------------------------------------------------------
__global__ __launch_bounds__(256) void norm_gather(
    const float* __restrict__ waves,
    const int*   __restrict__ pos,
    const int*   __restrict__ tile_cnt,
    const int*   __restrict__ tile_list,
    float* __restrict__ norm)
{
    const int blk = blockIdx.x;
    const int t   = blk >> 3;           // tile id
    const int s   = blk & 7;            // row-slice within tile
    const int Y0  = (t >> 5) * TS + s * (TS / SLICES);
    const int X0  = (t & 31) * TS;

    __shared__ int s_base[CAP + UNROLL];   // b * PH*PW
    __shared__ int s_r[CAP + UNROLL];
    __shared__ int s_c[CAP + UNROLL];

    const int count = min(tile_cnt[t], CAP);
    const int cpad  = (count + UNROLL - 1) & ~(UNROLL - 1);
    for (int i = threadIdx.x; i < cpad; i += 256) {
        if (i < count) {
            const int b = tile_list[t * CAP + i];
            s_base[i] = b * (PH * PW);
            s_r[i]    = pos[2 * b];
            s_c[i]    = pos[2 * b + 1];
        } else {
            s_base[i] = 0;              // dummy: mask is always 0; clamped
            s_r[i]    = 1 << 20;        // loads read waves[0..] (safe)
            s_c[i]    = 1 << 20;
        }
    }
    __syncthreads();

    const int x     = threadIdx.x & 63; // 64 lanes span one tile row
    const int phase = threadIdx.x >> 6; // 0..3
    const int X     = X0 + x;
    const int Ya    = Y0 + phase;       // first owned row
    const int Yb    = Ya + 4;           // second owned row

    const int MS = NB * PH * PW;        // mode stride in elements

    float acc_a = 0.0f;
    float acc_b = 0.0f;

    #pragma unroll UNROLL
    for (int i = 0; i < cpad; ++i) {
        const int dra = Ya - s_r[i];    // broadcast LDS reads (conflict-free)
        const int drb = Yb - s_r[i];
        const int dc  = X  - s_c[i];

        const bool va = ((unsigned)dc < (unsigned)PW) &
                        ((unsigned)dra < (unsigned)PH);
        const bool vb = ((unsigned)dc < (unsigned)PW) &
                        ((unsigned)drb < (unsigned)PH);

        // clamp into the patch -> loads always legal, mostly coalesced
        const int dcc  = min(max(dc, 0),  PW - 1);
        const int drac = min(max(dra, 0), PH - 1);
        const int drbc = min(max(drb, 0), PH - 1);

        const float* wa = waves + s_base[i] + drac * PW + dcc;
        const float* wb = waves + s_base[i] + drbc * PW + dcc;

        const float a0 = wa[0];
        const float a1 = wa[MS];
        const float a2 = wa[2 * MS];
        const float a3 = wa[3 * MS];
        const float b0 = wb[0];
        const float b1 = wb[MS];
        const float b2 = wb[2 * MS];
        const float b3 = wb[3 * MS];

        const float sa = a0 * a0 + a1 * a1 + a2 * a2 + a3 * a3;
        const float sb = b0 * b0 + b1 * b1 + b2 * b2 + b3 * b3;
        acc_a += va ? sa : 0.0f;        // v_cndmask + v_add (no branch)
        acc_b += vb ? sb : 0.0f;
    }

    norm[Ya * OW + X] = acc_a;          // every pixel written exactly once
    norm[Yb * OW + X] = acc_b;
}

extern "C" void kernel_launch(void* const* d_in, const int* in_sizes, int n_in,
                              void* d_out, int out_size, void* d_ws, size_t ws_size,
                              hipStream_t stream) {
    const float* obj   = (const float*)d_in[0];
    const float* waves = (const float*)d_in[1];
    const int*   pos   = (const int*)d_in[2];

    float* patches = (float*)d_out;                        // 16,777,216 elems
    float* norm    = (float*)d_out + (size_t)NB * PH * PW; // 4,194,304 elems

    // Workspace layout: [tile_cnt: NT ints][tile_list: NT*CAP ints] = 516 KB
    int* tile_cnt  = (int*)d_ws;
    int* tile_list = tile_cnt + NT;

    // ws is poisoned 0xAA each call -> zero the counters (4 KB, async).
    hipMemsetAsync(tile_cnt, 0, NT * sizeof(int), stream);

    const int quads = NB * PH * PW / 4;  // 4,194,304
    crop_and_bin<<<quads / 256, 256, 0, stream>>>(obj, pos, patches,
                                                  tile_cnt, tile_list);
    // Stream order guarantees tile lists are complete & visible device-wide.
    norm_gather<<<NT * SLICES, 256, 0, stream>>>(waves, pos, tile_cnt,
                                                 tile_list, norm);
}